// Round 1
// baseline (338.372 us; speedup 1.0000x reference)
//
#include <hip/hip_runtime.h>
#include <stdint.h>

#define H 128
#define TM 16
#define MAXDEG 24

typedef __attribute__((ext_vector_type(8))) short short8;
typedef __attribute__((ext_vector_type(4))) float f32x4;
typedef __attribute__((ext_vector_type(4))) int i32x4;

__device__ __forceinline__ unsigned short f2bf(float f) {
    union { float f; unsigned u; } v; v.f = f;
    unsigned u = v.u;
    u += 0x7fffu + ((u >> 16) & 1u);   // round-to-nearest-even
    return (unsigned short)(u >> 16);
}

__device__ __forceinline__ float bf2f(unsigned short u) {
    union { unsigned u; float f; } v; v.u = ((unsigned)u) << 16; return v.f;
}

__device__ __forceinline__ short8 cvt8(f32x4 a, f32x4 b) {
    short8 r;
    r[0] = (short)f2bf(a.x); r[1] = (short)f2bf(a.y);
    r[2] = (short)f2bf(a.z); r[3] = (short)f2bf(a.w);
    r[4] = (short)f2bf(b.x); r[5] = (short)f2bf(b.y);
    r[6] = (short)f2bf(b.z); r[7] = (short)f2bf(b.w);
    return r;
}

// ---------------------------------------------------------------------------
// CSR-lite build only. Entry = src | (type << 18). Overflow nodes
// (cnt > MAXDEG) handled by in-kernel edge rescan in the aggregate kernel.
// (No x->bf16 conversion pass anymore: gather reads fp32 x from L3 directly.)
// ---------------------------------------------------------------------------
__global__ __launch_bounds__(256) void prep_edges_kernel(
    const int* __restrict__ ei, const int* __restrict__ et,
    int* __restrict__ cnt, int* __restrict__ bucket, int E)
{
    int e = blockIdx.x * 256 + threadIdx.x;
    if (e >= E) return;
    int src = ei[e];
    int dst = ei[E + e];
    int t   = et[e];
    int pos = atomicAdd(&cnt[dst], 1);
    if (pos < MAXDEG) bucket[(size_t)dst * MAXDEG + pos] = src | (t << 18);
}

// ---------------------------------------------------------------------------
// Aggregate: one 16-lane group per node (8 feats/lane). fp32 gather of x rows
// + emb from LDS, fp32 accumulate, bf16 row write. No intra-loop barriers:
// pure TLP latency hiding. Grid-stride over node groups.
// ---------------------------------------------------------------------------
__global__ __launch_bounds__(256) void aggregate_kernel(
    const float* __restrict__ x, const float* __restrict__ emb,
    const int* __restrict__ cnt, const int* __restrict__ bucket,
    const int* __restrict__ ei, const int* __restrict__ et,
    unsigned short* __restrict__ aggb, int N, int E, int T)
{
    __shared__ __align__(16) float emb_s[16 * 132];   // padded stride 132

    const int tid = threadIdx.x;
    for (int i = tid; i < T * H; i += 256)
        emb_s[(i >> 7) * 132 + (i & 127)] = emb[i];
    __syncthreads();

    const int l = tid & 15;           // feature chunk: l*8 .. l*8+7
    const int nGroups = N >> 4;

    for (int g = blockIdx.x; g < nGroups; g += gridDim.x) {
        const int node = (g << 4) + (tid >> 4);

        const int* b = bucket + (size_t)node * MAXDEG;
        i32x4 p = *(const i32x4*)b;       // speculative: overlaps with cnt load
        const int c = cnt[node];

        f32x4 acc0 = {0.f, 0.f, 0.f, 0.f};
        f32x4 acc1 = {0.f, 0.f, 0.f, 0.f};

        if (c <= MAXDEG) {
            for (int i0 = 0; i0 < c; i0 += 4) {
                if (i0 > 0) p = *(const i32x4*)(b + i0);
                const int rem = c - i0;
                const bool h1 = rem > 1, h2 = rem > 2, h3 = rem > 3;

                f32x4 x00, x01, e00, e01, x10, x11, e10, e11;
                f32x4 x20, x21, e20, e21, x30, x31, e30, e31;
                {
                    int s = p.x & 0x3FFFF, t = p.x >> 18;
                    const float* xp = x + (size_t)s * H + l * 8;
                    const float* ep = emb_s + t * 132 + l * 8;
                    x00 = *(const f32x4*)xp;       x01 = *(const f32x4*)(xp + 4);
                    e00 = *(const f32x4*)ep;       e01 = *(const f32x4*)(ep + 4);
                }
                if (h1) {
                    int s = p.y & 0x3FFFF, t = p.y >> 18;
                    const float* xp = x + (size_t)s * H + l * 8;
                    const float* ep = emb_s + t * 132 + l * 8;
                    x10 = *(const f32x4*)xp;       x11 = *(const f32x4*)(xp + 4);
                    e10 = *(const f32x4*)ep;       e11 = *(const f32x4*)(ep + 4);
                }
                if (h2) {
                    int s = p.z & 0x3FFFF, t = p.z >> 18;
                    const float* xp = x + (size_t)s * H + l * 8;
                    const float* ep = emb_s + t * 132 + l * 8;
                    x20 = *(const f32x4*)xp;       x21 = *(const f32x4*)(xp + 4);
                    e20 = *(const f32x4*)ep;       e21 = *(const f32x4*)(ep + 4);
                }
                if (h3) {
                    int s = p.w & 0x3FFFF, t = p.w >> 18;
                    const float* xp = x + (size_t)s * H + l * 8;
                    const float* ep = emb_s + t * 132 + l * 8;
                    x30 = *(const f32x4*)xp;       x31 = *(const f32x4*)(xp + 4);
                    e30 = *(const f32x4*)ep;       e31 = *(const f32x4*)(ep + 4);
                }
                acc0 += x00 + e00;  acc1 += x01 + e01;
                if (h1) { acc0 += x10 + e10;  acc1 += x11 + e11; }
                if (h2) { acc0 += x20 + e20;  acc1 += x21 + e21; }
                if (h3) { acc0 += x30 + e30;  acc1 += x31 + e31; }
            }
        } else {
            // Overflow escape hatch (deg > MAXDEG): rescan full edge list.
            // Correct for any input; never triggered for Poisson(3) graphs.
            for (int e = 0; e < E; ++e) {
                if (ei[E + e] == node) {
                    int s = ei[e], t = et[e];
                    const float* xp = x + (size_t)s * H + l * 8;
                    const float* ep = emb_s + t * 132 + l * 8;
                    f32x4 v0 = *(const f32x4*)xp, v1 = *(const f32x4*)(xp + 4);
                    f32x4 w0 = *(const f32x4*)ep, w1 = *(const f32x4*)(ep + 4);
                    acc0 += v0 + w0;  acc1 += v1 + w1;
                }
            }
        }

        *(short8*)(aggb + (size_t)node * H + l * 8) = cvt8(acc0, acc1);
    }
}

// ---------------------------------------------------------------------------
// GEMM+LN: per 16-node tile stage A = [x fp32->bf16 | aggb bf16] (K=256),
// MFMA, bias+relu, LayerNorm, NT store. Uniform streaming work; no gather.
// ---------------------------------------------------------------------------
__global__ __launch_bounds__(256) void gemm_ln_kernel(
    const float* __restrict__ x, const unsigned short* __restrict__ aggb,
    const float* __restrict__ Wself, const float* __restrict__ bself,
    const float* __restrict__ Wmsg, const float* __restrict__ bmsg,
    const float* __restrict__ gamma, const float* __restrict__ beta,
    float* __restrict__ out, int nTiles)
{
    __shared__ __align__(16) short a_stage[TM * 264];  // 16 x (256+8 pad) bf16
    __shared__ __align__(16) float o_stage[TM * 132];  // 16 x (128+4 pad) f32

    const int tid  = threadIdx.x;
    const int wave = tid >> 6;
    const int lane = tid & 63;
    const int col  = lane & 15;
    const int quad = lane >> 4;

    // ---- B fragments (weights, bf16) into registers; once per block ----
    short8 bfrag[2][8];
    float bias[2];
#pragma unroll
    for (int s = 0; s < 2; ++s) {
        const int h = (wave * 2 + s) * 16 + col;
        bias[s] = bself[h] + bmsg[h];
#pragma unroll
        for (int kst = 0; kst < 8; ++kst) {
            const float* W = (kst < 4) ? Wself : Wmsg;
            const int k0 = (kst & 3) * 32 + quad * 8;
            const float* p = W + (size_t)h * H + k0;
            f32x4 w0 = *(const f32x4*)(p);
            f32x4 w1 = *(const f32x4*)(p + 4);
            bfrag[s][kst] = cvt8(w0, w1);
        }
    }

    const int lnode = tid >> 4;
    const int f0 = (tid & 15) * 8;
    f32x4 g0  = *(const f32x4*)(gamma + f0);
    f32x4 g1  = *(const f32x4*)(gamma + f0 + 4);
    f32x4 be0 = *(const f32x4*)(beta + f0);
    f32x4 be1 = *(const f32x4*)(beta + f0 + 4);

    const int node = tid >> 4;
    const int seg  = tid & 15;

    for (int tile = blockIdx.x; tile < nTiles; tile += gridDim.x) {
        const size_t rowBase = (size_t)tile * TM;

        // ---- stage A-tile: first 128 K from x (cvt), last 128 from aggb ----
        if (seg < 8) {
            const float* src = x + (rowBase + node) * H + seg * 16;
            f32x4 v0 = ((const f32x4*)src)[0];
            f32x4 v1 = ((const f32x4*)src)[1];
            f32x4 v2 = ((const f32x4*)src)[2];
            f32x4 v3 = ((const f32x4*)src)[3];
            *(short8*)&a_stage[node * 264 + seg * 16]     = cvt8(v0, v1);
            *(short8*)&a_stage[node * 264 + seg * 16 + 8] = cvt8(v2, v3);
        } else {
            const unsigned short* src = aggb + (rowBase + node) * H + (seg - 8) * 16;
            *(short8*)&a_stage[node * 264 + 128 + (seg - 8) * 16]     = *(const short8*)src;
            *(short8*)&a_stage[node * 264 + 128 + (seg - 8) * 16 + 8] = *(const short8*)(src + 8);
        }
        __syncthreads();

        // ---- MFMA over K=256 ----
        short8 afr[8];
#pragma unroll
        for (int kst = 0; kst < 8; ++kst)
            afr[kst] = *(const short8*)(&a_stage[col * 264 + kst * 32 + quad * 8]);

        f32x4 acc0 = {0.f, 0.f, 0.f, 0.f};
        f32x4 acc1 = {0.f, 0.f, 0.f, 0.f};
#pragma unroll
        for (int kst = 0; kst < 8; ++kst) {
            acc0 = __builtin_amdgcn_mfma_f32_16x16x32_bf16(afr[kst], bfrag[0][kst], acc0, 0, 0, 0);
            acc1 = __builtin_amdgcn_mfma_f32_16x16x32_bf16(afr[kst], bfrag[1][kst], acc1, 0, 0, 0);
        }

        // ---- bias + relu -> o_stage ----
#pragma unroll
        for (int s = 0; s < 2; ++s) {
            const int h = (wave * 2 + s) * 16 + col;
            f32x4 a = s ? acc1 : acc0;
#pragma unroll
            for (int r = 0; r < 4; ++r) {
                const int m = quad * 4 + r;
                float v = a[r] + bias[s];
                o_stage[m * 132 + h] = v > 0.f ? v : 0.f;
            }
        }
        __syncthreads();

        // ---- LayerNorm per node (16 lanes/node, 8 feats/lane) ----
        float v[8];
        float s1 = 0.f, s2 = 0.f;
#pragma unroll
        for (int j = 0; j < 8; ++j) {
            v[j] = o_stage[lnode * 132 + f0 + j];
            s1 += v[j];
            s2 += v[j] * v[j];
        }
#pragma unroll
        for (int m = 1; m < 16; m <<= 1) {
            s1 += __shfl_xor(s1, m, 64);
            s2 += __shfl_xor(s2, m, 64);
        }
        const float mu = s1 * (1.f / 128.f);
        const float var = s2 * (1.f / 128.f) - mu * mu;
        const float rstd = rsqrtf(var + 1e-5f);

        f32x4 o0, o1;
        o0.x = (v[0] - mu) * rstd * g0.x + be0.x;
        o0.y = (v[1] - mu) * rstd * g0.y + be0.y;
        o0.z = (v[2] - mu) * rstd * g0.z + be0.z;
        o0.w = (v[3] - mu) * rstd * g0.w + be0.w;
        o1.x = (v[4] - mu) * rstd * g1.x + be1.x;
        o1.y = (v[5] - mu) * rstd * g1.y + be1.y;
        o1.z = (v[6] - mu) * rstd * g1.z + be1.z;
        o1.w = (v[7] - mu) * rstd * g1.w + be1.w;

        float* dst = out + (rowBase + lnode) * H + f0;
        __builtin_nontemporal_store(o0, (f32x4*)dst);
        __builtin_nontemporal_store(o1, (f32x4*)(dst + 4));
    }
}

// ---------------------------------------------------------------------------
// Tier-C fallback: atomic scatter + fp32 gemm (agg staged in d_out).
// ---------------------------------------------------------------------------
__global__ __launch_bounds__(256) void scatter_kernel(
    const float* __restrict__ x, const int* __restrict__ ei,
    const int* __restrict__ et, const float* __restrict__ emb,
    float* __restrict__ agg, int E)
{
    int g = blockIdx.x * 256 + threadIdx.x;
    int e = g >> 5;
    int l = g & 31;
    if (e >= E) return;
    int src = ei[e];
    int dst = ei[E + e];
    int t   = et[e];
    f32x4 xv = *(const f32x4*)(x   + (size_t)src * H + l * 4);
    f32x4 ev = *(const f32x4*)(emb + (size_t)t   * H + l * 4);
    float* b = agg + (size_t)dst * H + l * 4;
    atomicAdd(b + 0, xv.x + ev.x);
    atomicAdd(b + 1, xv.y + ev.y);
    atomicAdd(b + 2, xv.z + ev.z);
    atomicAdd(b + 3, xv.w + ev.w);
}

__global__ __launch_bounds__(256) void gemm_ln_f32_kernel(
    const float* __restrict__ x,
    const float* __restrict__ Wself, const float* __restrict__ bself,
    const float* __restrict__ Wmsg, const float* __restrict__ bmsg,
    const float* __restrict__ gamma, const float* __restrict__ beta,
    float* __restrict__ out, int nTiles)
{
    __shared__ __align__(16) short a_stage[TM * 264];
    __shared__ __align__(16) float o_stage[TM * 132];

    const int tid  = threadIdx.x;
    const int wave = tid >> 6;
    const int lane = tid & 63;
    const int col  = lane & 15;
    const int quad = lane >> 4;

    short8 bfrag[2][8];
    float bias[2];
#pragma unroll
    for (int s = 0; s < 2; ++s) {
        const int h = (wave * 2 + s) * 16 + col;
        bias[s] = bself[h] + bmsg[h];
#pragma unroll
        for (int kst = 0; kst < 8; ++kst) {
            const float* W = (kst < 4) ? Wself : Wmsg;
            const int k0 = (kst & 3) * 32 + quad * 8;
            const float* p = W + (size_t)h * H + k0;
            f32x4 w0 = *(const f32x4*)(p);
            f32x4 w1 = *(const f32x4*)(p + 4);
            bfrag[s][kst] = cvt8(w0, w1);
        }
    }

    const int lnode = tid >> 4;
    const int f0 = (tid & 15) * 8;
    f32x4 g0  = *(const f32x4*)(gamma + f0);
    f32x4 g1  = *(const f32x4*)(gamma + f0 + 4);
    f32x4 be0 = *(const f32x4*)(beta + f0);
    f32x4 be1 = *(const f32x4*)(beta + f0 + 4);

    for (int tile = blockIdx.x; tile < nTiles; tile += gridDim.x) {
        const size_t rowBase = (size_t)tile * TM;
        {
            const int node = tid >> 4;
            const int seg  = tid & 15;
            const int k0   = seg * 16;
            const float* src = (seg < 8)
                ? (x   + (rowBase + node) * H + k0)
                : (out + (rowBase + node) * H + (k0 - 128));
            f32x4 v0 = ((const f32x4*)src)[0];
            f32x4 v1 = ((const f32x4*)src)[1];
            f32x4 v2 = ((const f32x4*)src)[2];
            f32x4 v3 = ((const f32x4*)src)[3];
            *(short8*)(&a_stage[node * 264 + k0])     = cvt8(v0, v1);
            *(short8*)(&a_stage[node * 264 + k0 + 8]) = cvt8(v2, v3);
        }
        __syncthreads();

        short8 afr[8];
#pragma unroll
        for (int kst = 0; kst < 8; ++kst)
            afr[kst] = *(const short8*)(&a_stage[col * 264 + kst * 32 + quad * 8]);

        f32x4 acc0 = {0.f, 0.f, 0.f, 0.f};
        f32x4 acc1 = {0.f, 0.f, 0.f, 0.f};
#pragma unroll
        for (int kst = 0; kst < 8; ++kst) {
            acc0 = __builtin_amdgcn_mfma_f32_16x16x32_bf16(afr[kst], bfrag[0][kst], acc0, 0, 0, 0);
            acc1 = __builtin_amdgcn_mfma_f32_16x16x32_bf16(afr[kst], bfrag[1][kst], acc1, 0, 0, 0);
        }

#pragma unroll
        for (int s = 0; s < 2; ++s) {
            const int h = (wave * 2 + s) * 16 + col;
            f32x4 a = s ? acc1 : acc0;
#pragma unroll
            for (int r = 0; r < 4; ++r) {
                const int m = quad * 4 + r;
                float v = a[r] + bias[s];
                o_stage[m * 132 + h] = v > 0.f ? v : 0.f;
            }
        }
        __syncthreads();

        float v[8];
        float s1 = 0.f, s2 = 0.f;
#pragma unroll
        for (int j = 0; j < 8; ++j) {
            v[j] = o_stage[lnode * 132 + f0 + j];
            s1 += v[j];
            s2 += v[j] * v[j];
        }
#pragma unroll
        for (int m = 1; m < 16; m <<= 1) {
            s1 += __shfl_xor(s1, m, 64);
            s2 += __shfl_xor(s2, m, 64);
        }
        const float mu = s1 * (1.f / 128.f);
        const float var = s2 * (1.f / 128.f) - mu * mu;
        const float rstd = rsqrtf(var + 1e-5f);

        f32x4 o0, o1;
        o0.x = (v[0] - mu) * rstd * g0.x + be0.x;
        o0.y = (v[1] - mu) * rstd * g0.y + be0.y;
        o0.z = (v[2] - mu) * rstd * g0.z + be0.z;
        o0.w = (v[3] - mu) * rstd * g0.w + be0.w;
        o1.x = (v[4] - mu) * rstd * g1.x + be1.x;
        o1.y = (v[5] - mu) * rstd * g1.y + be1.y;
        o1.z = (v[6] - mu) * rstd * g1.z + be1.z;
        o1.w = (v[7] - mu) * rstd * g1.w + be1.w;

        float* dst = out + (rowBase + lnode) * H + f0;
        *(f32x4*)(dst)     = o0;
        *(f32x4*)(dst + 4) = o1;
    }
}

extern "C" void kernel_launch(void* const* d_in, const int* in_sizes, int n_in,
                              void* d_out, int out_size, void* d_ws, size_t ws_size,
                              hipStream_t stream) {
    const float* x     = (const float*)d_in[0];
    const int*   ei    = (const int*)d_in[1];
    const int*   et    = (const int*)d_in[2];
    const float* emb   = (const float*)d_in[3];
    const float* Wself = (const float*)d_in[4];
    const float* bself = (const float*)d_in[5];
    const float* Wmsg  = (const float*)d_in[6];
    const float* bmsg  = (const float*)d_in[7];
    const float* gamma = (const float*)d_in[8];
    const float* beta  = (const float*)d_in[9];
    float* out = (float*)d_out;

    const int E = in_sizes[2];
    const int N = in_sizes[0] / H;
    const int T = in_sizes[3] / H;
    const int nTiles = N / TM;

    auto rnd = [](size_t b) { return (b + 255) & ~(size_t)255; };
    const size_t sz_agg = rnd((size_t)N * H * 2);
    const size_t sz_cnt = rnd((size_t)N * 4);
    const size_t sz_bkt = rnd((size_t)N * MAXDEG * 4);
    const size_t needA = sz_agg + sz_cnt + sz_bkt;

    const bool tierA = (ws_size >= needA) && (N <= (1 << 18)) && (T <= 16)
                       && (N % TM == 0);

    if (tierA) {
        uint8_t* p = (uint8_t*)d_ws;
        unsigned short* aggb = (unsigned short*)p;  p += sz_agg;
        int* cnt    = (int*)p;                      p += sz_cnt;
        int* bucket = (int*)p;

        hipMemsetAsync(cnt, 0, (size_t)N * sizeof(int), stream);

        if (E > 0) {
            prep_edges_kernel<<<(E + 255) / 256, 256, 0, stream>>>(
                ei, et, cnt, bucket, E);
        }

        const int nGroups = N >> 4;
        int aggGrid = nGroups < 4096 ? nGroups : 4096;
        aggregate_kernel<<<aggGrid, 256, 0, stream>>>(
            x, emb, cnt, bucket, ei, et, aggb, N, E, T);

        int gemmGrid = nTiles < 2048 ? nTiles : 2048;
        gemm_ln_kernel<<<gemmGrid, 256, 0, stream>>>(
            x, aggb, Wself, bself, Wmsg, bmsg, gamma, beta, out, nTiles);
    } else {
        // Tier C: atomic scatter into d_out, then fp32 gemm reading agg from d_out.
        hipMemsetAsync(out, 0, (size_t)N * H * sizeof(float), stream);
        const long long sthreads = (long long)E * 32;
        scatter_kernel<<<(int)((sthreads + 255) / 256), 256, 0, stream>>>(
            x, ei, et, emb, out, E);
        int grid = 2500;
        if (grid > nTiles) grid = nTiles;
        gemm_ln_f32_kernel<<<grid, 256, 0, stream>>>(
            x, Wself, bself, Wmsg, bmsg, gamma, beta, out, nTiles);
    }
}